// Round 1
// baseline (10635.011 us; speedup 1.0000x reference)
//
#include <hip/hip_runtime.h>
#include <math.h>

#define T_STEPS 64
#define A_DIM   16
#define SEQ     1024      // T*A
#define HE      256       // encoder hidden per direction
#define DH      512       // decoder hidden
#define GE      1024      // 4*HE
#define GD      2048      // 4*DH

__device__ __forceinline__ float sigf(float x) { return 1.f / (1.f + __expf(-x)); }

// ---------------------------------------------------------------------------
// Embedding / decoder-input assembly
// ---------------------------------------------------------------------------
__global__ void k_embed(const int* __restrict__ lattice, const int* __restrict__ inputs,
                        const int* __restrict__ gold, const int* __restrict__ sos,
                        const float* __restrict__ lat_emb, const float* __restrict__ in_emb,
                        float* __restrict__ x, float* __restrict__ decin)
{
    int idx = blockIdx.x * 256 + threadIdx.x;
    if (idx < SEQ * 256) {
        int row = idx >> 8, e = idx & 255;
        int f = e >> 6, eo = e & 63;
        int id = lattice[row * 4 + f];
        x[idx] = lat_emb[id * 64 + eo];
    } else {
        int k = idx - SEQ * 256;
        if (k < T_STEPS * 512) {
            int t = k >> 9, d = k & 511;
            float val;
            if (d < 256) {
                int f = d >> 6, eo = d & 63;
                int id = (t == 0) ? sos[f]
                                  : lattice[(((t - 1) * A_DIM) + gold[t - 1]) * 4 + f];
                val = lat_emb[id * 64 + eo];
            } else {
                val = in_emb[inputs[t] * 256 + (d - 256)];
            }
            decin[k] = val;
        }
    }
}

// ---------------------------------------------------------------------------
// Generic fp32 GEMM: C[m,n] = bias[n] + sum_k A[m*lda+k] * B[n*ldbn + k*ldbk]
// 64x64 tile, 4x4 microtile, K-chunks of 16.
// ---------------------------------------------------------------------------
__global__ __launch_bounds__(256) void k_gemm(
    const float* __restrict__ A, int lda, long sA,
    const float* __restrict__ B, int ldbn, int ldbk, long sB,
    const float* __restrict__ bias, int sBias,
    float* __restrict__ C, int ldc, long sC,
    int M, int N, int K)
{
    int b = blockIdx.z;
    A += b * sA; B += b * sB; C += b * sC;
    if (bias) bias += (long)b * sBias;
    int n0 = blockIdx.x * 64, m0 = blockIdx.y * 64;
    __shared__ float As[64][17];
    __shared__ float Bs[64][17];
    int tid = threadIdx.x;
    int tn = tid & 15, tm = tid >> 4;
    float acc[4][4] = {};
    int lk = tid & 15, lr = tid >> 4;
    for (int k0 = 0; k0 < K; k0 += 16) {
#pragma unroll
        for (int i = 0; i < 4; i++) {
            int row = lr + i * 16;
            int am = m0 + row;
            As[row][lk] = (am < M) ? A[(long)am * lda + k0 + lk] : 0.f;
            int bn = n0 + row;
            Bs[row][lk] = (bn < N) ? B[(long)bn * ldbn + (long)(k0 + lk) * ldbk] : 0.f;
        }
        __syncthreads();
#pragma unroll
        for (int k = 0; k < 16; k++) {
            float av[4], bv[4];
#pragma unroll
            for (int i = 0; i < 4; i++) av[i] = As[tm * 4 + i][k];
#pragma unroll
            for (int j = 0; j < 4; j++) bv[j] = Bs[tn * 4 + j][k];
#pragma unroll
            for (int i = 0; i < 4; i++)
#pragma unroll
                for (int j = 0; j < 4; j++) acc[i][j] += av[i] * bv[j];
        }
        __syncthreads();
    }
#pragma unroll
    for (int i = 0; i < 4; i++) {
        int m = m0 + tm * 4 + i;
        if (m >= M) continue;
#pragma unroll
        for (int j = 0; j < 4; j++) {
            int n = n0 + tn * 4 + j;
            if (n < N) C[(long)m * ldc + n] = acc[i][j] + (bias ? bias[n] : 0.f);
        }
    }
}

// ---------------------------------------------------------------------------
// Encoder biLSTM recurrence, one layer. 8 blocks: 0-3 = fwd team, 4-7 = bwd.
// Each block holds 256 rows of Whh (K=256) in VGPRs; 4-block per-step barrier
// through device-scope flags. pre[] already contains x@Wih^T + b.
// ---------------------------------------------------------------------------
__global__ __launch_bounds__(256, 1) void k_rec_enc(
    const float* __restrict__ pre,   // [2][SEQ][GE]
    const float* __restrict__ Whh,   // [2][GE][HE]
    float* __restrict__ y,           // [SEQ][2*HE]
    float* __restrict__ hfin,        // [512] (this layer's slot)
    float* __restrict__ cfin,        // [512]
    float* __restrict__ hbuf_all,    // [2][HE]
    int* __restrict__ flags)         // per-launch region, block b at [b*16]
{
    const int tid = threadIdx.x;
    const int bid = blockIdx.x;
    const int r = bid & 3, dir = bid >> 2;
    const bool fwd = (dir == 0);
    const int jj = tid & 63;
    const int j = r * 64 + jj;                 // h index this row contributes to
    const int row = (tid >> 6) * HE + j;       // gate row (i,f,g,o blocks)
    const float* pre_d = pre + (long)dir * SEQ * GE;
    float* hbuf = hbuf_all + dir * HE;

    float w[HE];
    {
        const float4* wr = (const float4*)(Whh + (long)dir * GE * HE + (long)row * HE);
#pragma unroll
        for (int i = 0; i < HE / 4; i++) ((float4*)w)[i] = wr[i];
    }

    __shared__ __align__(16) float hs[HE];
    __shared__ float gl[256];
    hs[tid & (HE - 1)] = 0.f;
    __syncthreads();

    float c = 0.f;
    float pre_cur = pre_d[(long)(fwd ? 0 : SEQ - 1) * GE + row];

    for (int s = 0; s < SEQ; s++) {
        int t = fwd ? s : SEQ - 1 - s;
        float a0 = 0, a1 = 0, a2 = 0, a3 = 0;
#pragma unroll
        for (int k = 0; k < HE; k += 16) {
            float4 h0 = *(const float4*)&hs[k];
            float4 h1 = *(const float4*)&hs[k + 4];
            float4 h2 = *(const float4*)&hs[k + 8];
            float4 h3 = *(const float4*)&hs[k + 12];
            a0 += w[k + 0] * h0.x + w[k + 1] * h0.y + w[k + 2] * h0.z + w[k + 3] * h0.w;
            a1 += w[k + 4] * h1.x + w[k + 5] * h1.y + w[k + 6] * h1.z + w[k + 7] * h1.w;
            a2 += w[k + 8] * h2.x + w[k + 9] * h2.y + w[k + 10] * h2.z + w[k + 11] * h2.w;
            a3 += w[k + 12] * h3.x + w[k + 13] * h3.y + w[k + 14] * h3.z + w[k + 15] * h3.w;
        }
        float g = pre_cur + ((a0 + a1) + (a2 + a3));
        if (s + 1 < SEQ) {                       // software prefetch next step's pre
            int tn = fwd ? t + 1 : t - 1;
            pre_cur = pre_d[(long)tn * GE + row];
        }
        gl[tid] = g;
        __syncthreads();
        if (tid < 64) {
            float gi = gl[jj], gf = gl[64 + jj], gg = gl[128 + jj], go = gl[192 + jj];
            c = sigf(gf) * c + sigf(gi) * tanhf(gg);
            float h = sigf(go) * tanhf(c);
            hs[j] = h;
            hbuf[j] = h;
            y[(long)t * (2 * HE) + dir * HE + j] = h;
            __threadfence();
        }
        __syncthreads();
        if (tid == 0)
            __hip_atomic_store(&flags[bid * 16], s + 1, __ATOMIC_RELEASE, __HIP_MEMORY_SCOPE_AGENT);
        if (tid < 3) {
            int p = tid + (tid >= r ? 1 : 0);
            const int* fp = &flags[(dir * 4 + p) * 16];
            while (__hip_atomic_load(fp, __ATOMIC_ACQUIRE, __HIP_MEMORY_SCOPE_AGENT) < s + 1)
                __builtin_amdgcn_s_sleep(1);
        }
        __syncthreads();
        if ((tid >> 6) != r) hs[tid] = hbuf[tid];   // refresh partner h slices
        __syncthreads();
    }
    if (tid < 64) {
        hfin[dir * HE + j] = hs[j];
        cfin[dir * HE + j] = c;
    }
}

// ---------------------------------------------------------------------------
// Decoder LSTM recurrence, one layer. 16 blocks; block r owns h[r*32..r*32+32).
// Each row (K=512) split across 2 threads (256 weights each, in VGPRs).
// ---------------------------------------------------------------------------
__global__ __launch_bounds__(256, 1) void k_rec_dec(
    const float* __restrict__ pre,    // [64][GD] (= in @ Wih^T + b)
    const float* __restrict__ Whh,    // [GD][DH] (layer-selected)
    const float* __restrict__ hinit,  // [512]
    const float* __restrict__ cinit,  // [512]
    float* __restrict__ hseq,         // [64][512]
    float* __restrict__ hbuf,         // [512]
    int* __restrict__ flags)
{
    const int tid = threadIdx.x, r = blockIdx.x;
    const int kh = tid >> 7, rem = tid & 127;
    const int q = rem >> 5, jj = rem & 31;
    const int row = q * DH + r * 32 + jj;
    const int k0 = kh * 256;

    float w[256];
    {
        const float4* wr = (const float4*)(Whh + (long)row * DH + k0);
#pragma unroll
        for (int i = 0; i < 64; i++) ((float4*)w)[i] = wr[i];
    }
    __shared__ __align__(16) float hs[DH];
    __shared__ float part[256];
    __shared__ float gate[128];
    hs[tid] = hinit[tid];
    hs[tid + 256] = hinit[tid + 256];
    float c = (tid < 32) ? cinit[r * 32 + tid] : 0.f;
    float pre_cur = (tid < 128) ? pre[row] : 0.f;
    __syncthreads();

    for (int s = 0; s < T_STEPS; s++) {
        float a0 = 0, a1 = 0, a2 = 0, a3 = 0;
#pragma unroll
        for (int k = 0; k < 256; k += 16) {
            float4 h0 = *(const float4*)&hs[k0 + k];
            float4 h1 = *(const float4*)&hs[k0 + k + 4];
            float4 h2 = *(const float4*)&hs[k0 + k + 8];
            float4 h3 = *(const float4*)&hs[k0 + k + 12];
            a0 += w[k + 0] * h0.x + w[k + 1] * h0.y + w[k + 2] * h0.z + w[k + 3] * h0.w;
            a1 += w[k + 4] * h1.x + w[k + 5] * h1.y + w[k + 6] * h1.z + w[k + 7] * h1.w;
            a2 += w[k + 8] * h2.x + w[k + 9] * h2.y + w[k + 10] * h2.z + w[k + 11] * h2.w;
            a3 += w[k + 12] * h3.x + w[k + 13] * h3.y + w[k + 14] * h3.z + w[k + 15] * h3.w;
        }
        part[tid] = (a0 + a1) + (a2 + a3);
        __syncthreads();
        if (tid < 128) {
            float g = part[tid] + part[tid + 128] + pre_cur;
            if (s + 1 < T_STEPS) pre_cur = pre[(long)(s + 1) * GD + row];
            gate[tid] = g;
        }
        __syncthreads();
        if (tid < 32) {
            int j = r * 32 + tid;
            float gi = gate[tid], gf = gate[32 + tid], gg = gate[64 + tid], go = gate[96 + tid];
            c = sigf(gf) * c + sigf(gi) * tanhf(gg);
            float h = sigf(go) * tanhf(c);
            hs[j] = h;
            hbuf[j] = h;
            hseq[(long)s * DH + j] = h;
            __threadfence();
        }
        __syncthreads();
        if (tid == 0)
            __hip_atomic_store(&flags[r * 16], s + 1, __ATOMIC_RELEASE, __HIP_MEMORY_SCOPE_AGENT);
        if (tid < 15) {
            int p = tid + (tid >= r ? 1 : 0);
            const int* fp = &flags[p * 16];
            while (__hip_atomic_load(fp, __ATOMIC_ACQUIRE, __HIP_MEMORY_SCOPE_AGENT) < s + 1)
                __builtin_amdgcn_s_sleep(1);
        }
        __syncthreads();
        if ((tid >> 5) != r) hs[tid] = hbuf[tid];
        if (((tid + 256) >> 5) != r) hs[tid + 256] = hbuf[tid + 256];
        __syncthreads();
    }
}

// ---------------------------------------------------------------------------
// Attention readout: scores[t,a] = (a<len) ? v . tanh(encK[t,a,:] + q[t,:]) : -1e10
// ---------------------------------------------------------------------------
__global__ void k_attn(const float* __restrict__ encK, const float* __restrict__ qs,
                       const float* __restrict__ v, const int* __restrict__ alens,
                       float* __restrict__ out)
{
    int t = blockIdx.x;
    int tid = threadIdx.x;
    int wave = tid >> 6, lane = tid & 63;
    int len = alens[t];
    const float* qt = qs + t * 256;
    for (int a = wave; a < A_DIM; a += 4) {
        const float* ek = encK + (long)(t * A_DIM + a) * 256;
        float sum = 0.f;
#pragma unroll
        for (int e = 0; e < 4; e++) {
            int d = lane * 4 + e;
            sum += v[d] * tanhf(ek[d] + qt[d]);
        }
        for (int off = 32; off; off >>= 1) sum += __shfl_down(sum, off, 64);
        if (lane == 0) out[t * A_DIM + a] = (a < len) ? sum : -1e10f;
    }
}

// ---------------------------------------------------------------------------
extern "C" void kernel_launch(void* const* d_in, const int* in_sizes, int n_in,
                              void* d_out, int out_size, void* d_ws, size_t ws_size,
                              hipStream_t stream)
{
    (void)in_sizes; (void)n_in; (void)out_size; (void)ws_size;
    const int*   lattice = (const int*)d_in[0];
    const int*   alens   = (const int*)d_in[1];
    const int*   inputs  = (const int*)d_in[2];
    const int*   gold    = (const int*)d_in[4];
    const int*   sos     = (const int*)d_in[5];
    const float* lat_emb = (const float*)d_in[6];
    const float* in_emb  = (const float*)d_in[7];
    const float* Wih0    = (const float*)d_in[8];
    const float* Whh0    = (const float*)d_in[9];
    const float* b0      = (const float*)d_in[10];
    const float* Wih1    = (const float*)d_in[11];
    const float* Whh1    = (const float*)d_in[12];
    const float* b1      = (const float*)d_in[13];
    const float* dWih    = (const float*)d_in[14];
    const float* dWhh    = (const float*)d_in[15];
    const float* db      = (const float*)d_in[16];
    const float* Wq      = (const float*)d_in[17];
    const float* Wk      = (const float*)d_in[18];
    const float* av      = (const float*)d_in[19];
    float* out = (float*)d_out;
    float* ws  = (float*)d_ws;

    // ws layout (floats)
    int*   flagsI = (int*)ws;                  // 1024 ints (4 regions x 16 blocks x 16)
    float* hbuf   = ws + 1024;                 // 1024
    float* x      = ws + 2048;                 // 262144
    float* pre    = ws + 264192;               // 2097152 (shared: pre0 then pre1)
    float* y0     = ws + 2361344;              // 524288
    float* enc    = ws + 2885632;              // 524288
    float* hdec   = ws + 3409920;              // 1024  [2][512]
    float* cdec   = ws + 3410944;              // 1024
    float* decin  = ws + 3411968;              // 32768 [64][512]
    float* dpre   = ws + 3444736;              // 131072 (shared: dpre0 then dpre1)
    float* h0seq  = ws + 3575808;              // 32768
    float* h1seq  = ws + 3608576;              // 32768
    float* encK   = ws + 3641344;              // 262144
    float* qseq   = ws + 3903488;              // 16384

    // zero sync flags + hbuf (ws is poisoned 0xAA before every launch)
    hipMemsetAsync(d_ws, 0, 8192, stream);

    k_embed<<<1152, 256, 0, stream>>>(lattice, inputs, gold, sos, lat_emb, in_emb, x, decin);

    // pre0[d] = x @ Wih0[d]^T + b0[d]
    k_gemm<<<dim3(16, 16, 2), 256, 0, stream>>>(
        x, 256, 0L, Wih0, 256, 1, (long)GE * 256, b0, GE,
        pre, GE, (long)SEQ * GE, SEQ, GE, 256);
    k_rec_enc<<<8, 256, 0, stream>>>(pre, Whh0, y0, hdec, cdec, hbuf, flagsI + 0 * 256);

    // pre1[d] = y0 @ Wih1[d]^T + b1[d]
    k_gemm<<<dim3(16, 16, 2), 256, 0, stream>>>(
        y0, 512, 0L, Wih1, 512, 1, (long)GE * 512, b1, GE,
        pre, GE, (long)SEQ * GE, SEQ, GE, 512);
    k_rec_enc<<<8, 256, 0, stream>>>(pre, Whh1, enc, hdec + 512, cdec + 512, hbuf, flagsI + 1 * 256);

    // encK = enc @ Wk   (Wk is [512,256] K-major)
    k_gemm<<<dim3(4, 16, 1), 256, 0, stream>>>(
        enc, 512, 0L, Wk, 1, 256, 0L, nullptr, 0,
        encK, 256, 0L, SEQ, 256, 512);

    // dpre0 = decin @ dWih[0]^T + db[0]
    k_gemm<<<dim3(32, 1, 1), 256, 0, stream>>>(
        decin, 512, 0L, dWih, 512, 1, 0L, db, 0,
        dpre, GD, 0L, T_STEPS, GD, 512);
    k_rec_dec<<<16, 256, 0, stream>>>(dpre, dWhh, hdec, cdec, h0seq, hbuf, flagsI + 2 * 256);

    // dpre1 = h0seq @ dWih[1]^T + db[1]
    k_gemm<<<dim3(32, 1, 1), 256, 0, stream>>>(
        h0seq, 512, 0L, dWih + (long)GD * 512, 512, 1, 0L, db + GD, 0,
        dpre, GD, 0L, T_STEPS, GD, 512);
    k_rec_dec<<<16, 256, 0, stream>>>(dpre, dWhh + (long)GD * 512, hdec + 512, cdec + 512,
                                      h1seq, hbuf, flagsI + 3 * 256);

    // q = h1seq @ Wq   (Wq is [512,256] K-major)
    k_gemm<<<dim3(4, 1, 1), 256, 0, stream>>>(
        h1seq, 512, 0L, Wq, 1, 256, 0L, nullptr, 0,
        qseq, 256, 0L, T_STEPS, 256, 512);

    k_attn<<<64, 256, 0, stream>>>(encK, qseq, av, alens, out);
}

// Round 2
// 3958.501 us; speedup vs baseline: 2.6866x; 2.6866x over previous
//
#include <hip/hip_runtime.h>
#include <math.h>

#define T_STEPS 64
#define A_DIM   16
#define SEQ     1024      // T*A
#define HE      256       // encoder hidden per direction
#define DH      512       // decoder hidden
#define GE      1024      // 4*HE
#define GD      2048      // 4*DH

typedef _Float16 h2_t __attribute__((ext_vector_type(2)));

__device__ __forceinline__ float sigf(float x) { return 1.f / (1.f + __expf(-x)); }
// tanh via exp2-based __expf; args here are bounded (|x| < ~4) so no overflow path.
__device__ __forceinline__ float tanh_fast(float x) {
    float e = __expf(-2.f * x);
    return (1.f - e) / (1.f + e);
}

__device__ __forceinline__ float fdot2f(h2_t a, h2_t b, float c) {
#if defined(__has_builtin) && __has_builtin(__builtin_amdgcn_fdot2)
    return __builtin_amdgcn_fdot2(a, b, c, false);
#else
    return c + (float)a.x * (float)b.x + (float)a.y * (float)b.y;
#endif
}

__device__ __forceinline__ float poll_comm(const float* p) {
    float v;
    do {
        v = __hip_atomic_load(p, __ATOMIC_RELAXED, __HIP_MEMORY_SCOPE_AGENT);
    } while (v == 0.f);
    return v - 4.0f;
}

__device__ __forceinline__ void post_comm(float* p, float h) {
    __hip_atomic_store(p, h + 4.0f, __ATOMIC_RELAXED, __HIP_MEMORY_SCOPE_AGENT);
}

// ---------------------------------------------------------------------------
// Embedding / decoder-input assembly
// ---------------------------------------------------------------------------
__global__ void k_embed(const int* __restrict__ lattice, const int* __restrict__ inputs,
                        const int* __restrict__ gold, const int* __restrict__ sos,
                        const float* __restrict__ lat_emb, const float* __restrict__ in_emb,
                        float* __restrict__ x, float* __restrict__ decin)
{
    int idx = blockIdx.x * 256 + threadIdx.x;
    if (idx < SEQ * 256) {
        int row = idx >> 8, e = idx & 255;
        int f = e >> 6, eo = e & 63;
        int id = lattice[row * 4 + f];
        x[idx] = lat_emb[id * 64 + eo];
    } else {
        int k = idx - SEQ * 256;
        if (k < T_STEPS * 512) {
            int t = k >> 9, d = k & 511;
            float val;
            if (d < 256) {
                int f = d >> 6, eo = d & 63;
                int id = (t == 0) ? sos[f]
                                  : lattice[(((t - 1) * A_DIM) + gold[t - 1]) * 4 + f];
                val = lat_emb[id * 64 + eo];
            } else {
                val = in_emb[inputs[t] * 256 + (d - 256)];
            }
            decin[k] = val;
        }
    }
}

// ---------------------------------------------------------------------------
// Generic fp32 GEMM: C[m,n] = bias[n] + sum_k A[m*lda+k] * B[n*ldbn + k*ldbk]
// ---------------------------------------------------------------------------
__global__ __launch_bounds__(256) void k_gemm(
    const float* __restrict__ A, int lda, long sA,
    const float* __restrict__ B, int ldbn, int ldbk, long sB,
    const float* __restrict__ bias, int sBias,
    float* __restrict__ C, int ldc, long sC,
    int M, int N, int K)
{
    int b = blockIdx.z;
    A += b * sA; B += b * sB; C += b * sC;
    if (bias) bias += (long)b * sBias;
    int n0 = blockIdx.x * 64, m0 = blockIdx.y * 64;
    __shared__ float As[64][17];
    __shared__ float Bs[64][17];
    int tid = threadIdx.x;
    int tn = tid & 15, tm = tid >> 4;
    float acc[4][4] = {};
    int lk = tid & 15, lr = tid >> 4;
    for (int k0 = 0; k0 < K; k0 += 16) {
#pragma unroll
        for (int i = 0; i < 4; i++) {
            int row = lr + i * 16;
            int am = m0 + row;
            As[row][lk] = (am < M) ? A[(long)am * lda + k0 + lk] : 0.f;
            int bn = n0 + row;
            Bs[row][lk] = (bn < N) ? B[(long)bn * ldbn + (long)(k0 + lk) * ldbk] : 0.f;
        }
        __syncthreads();
#pragma unroll
        for (int k = 0; k < 16; k++) {
            float av[4], bv[4];
#pragma unroll
            for (int i = 0; i < 4; i++) av[i] = As[tm * 4 + i][k];
#pragma unroll
            for (int j = 0; j < 4; j++) bv[j] = Bs[tn * 4 + j][k];
#pragma unroll
            for (int i = 0; i < 4; i++)
#pragma unroll
                for (int j = 0; j < 4; j++) acc[i][j] += av[i] * bv[j];
        }
        __syncthreads();
    }
#pragma unroll
    for (int i = 0; i < 4; i++) {
        int m = m0 + tm * 4 + i;
        if (m >= M) continue;
#pragma unroll
        for (int j = 0; j < 4; j++) {
            int n = n0 + tn * 4 + j;
            if (n < N) C[(long)m * ldc + n] = acc[i][j] + (bias ? bias[n] : 0.f);
        }
    }
}

// ---------------------------------------------------------------------------
// Encoder biLSTM recurrence, one layer. 8 blocks: 0-3 fwd team, 4-7 bwd.
// f16 weights in VGPRs (v_dot2_f32_f16), fp32 accumulate. Cross-block h
// exchange via self-validating comm words (h+4, buffer pre-zeroed): one
// relaxed agent store by the producer, one polled load by the consumer.
// ---------------------------------------------------------------------------
__global__ __launch_bounds__(256, 1) void k_rec_enc(
    const float* __restrict__ pre,   // [2][SEQ][GE]
    const float* __restrict__ Whh,   // [2][GE][HE]
    float* __restrict__ y,           // [SEQ][512]
    float* __restrict__ hfin,        // [512] this layer's slot
    float* __restrict__ cfin,        // [512]
    float* __restrict__ comm)        // [2][SEQ][HE], zeroed before launch
{
    const int tid = threadIdx.x, bid = blockIdx.x;
    const int r = bid & 3, dir = bid >> 2;
    const bool fwd = (dir == 0);
    const int jj = tid & 63, j = r * 64 + jj;
    const int row = (tid >> 6) * HE + j;          // gate row (i,f,g,o blocks)
    const float* pre_d = pre + (long)dir * SEQ * GE;
    float* comm_d = comm + (long)dir * SEQ * HE;

    h2_t w2[128];
    {
        const float4* wr = (const float4*)(Whh + (long)dir * GE * HE + (long)row * HE);
#pragma unroll
        for (int i = 0; i < 64; i++) {
            float4 v = wr[i];
            w2[2 * i]     = h2_t{(_Float16)v.x, (_Float16)v.y};
            w2[2 * i + 1] = h2_t{(_Float16)v.z, (_Float16)v.w};
        }
    }

    __shared__ __align__(16) _Float16 hsArr[HE];
    __shared__ float gl[256];
    hsArr[tid] = (_Float16)0.f;
    __syncthreads();

    float c = 0.f, h_cur = 0.f;
    float pre_cur = pre_d[(long)(fwd ? 0 : SEQ - 1) * GE + row];

    for (int s = 0; s < SEQ; s++) {
        const int t = fwd ? s : SEQ - 1 - s;
        float acc = 0.f;
        const float4* hv = (const float4*)hsArr;
#pragma unroll
        for (int kk = 0; kk < 32; kk++) {
            float4 blk = hv[kk];
            const h2_t* hp = (const h2_t*)&blk;
            acc = fdot2f(w2[4 * kk + 0], hp[0], acc);
            acc = fdot2f(w2[4 * kk + 1], hp[1], acc);
            acc = fdot2f(w2[4 * kk + 2], hp[2], acc);
            acc = fdot2f(w2[4 * kk + 3], hp[3], acc);
        }
        gl[tid] = pre_cur + acc;
        if (s + 1 < SEQ) pre_cur = pre_d[(long)(fwd ? t + 1 : t - 1) * GE + row];
        __syncthreads();
        if (tid < 64) {
            float gi = gl[jj], gf = gl[64 + jj], gg = gl[128 + jj], go = gl[192 + jj];
            c = sigf(gf) * c + sigf(gi) * tanh_fast(gg);
            h_cur = sigf(go) * tanh_fast(c);
            post_comm(&comm_d[(long)t * HE + j], h_cur);   // publish FIRST
            y[(long)t * 512 + dir * HE + j] = h_cur;
            hsArr[j] = (_Float16)h_cur;                    // own slice direct
        }
        if (s + 1 < SEQ && tid < 192) {                    // fetch 192 remote
            int idx = (r * 64 + 64 + tid) & 255;
            hsArr[idx] = (_Float16)poll_comm(&comm_d[(long)t * HE + idx]);
        }
        __syncthreads();
    }
    if (tid < 64) {
        hfin[dir * HE + j] = h_cur;
        cfin[dir * HE + j] = c;
    }
}

// ---------------------------------------------------------------------------
// Decoder LSTM recurrence, one layer. 16 blocks; block r owns h[r*32..+32).
// Row K=512 split across thread pairs (256 f16 weights each). Same
// self-validating comm sync as the encoder.
// ---------------------------------------------------------------------------
__global__ __launch_bounds__(256, 1) void k_rec_dec(
    const float* __restrict__ pre,    // [64][GD]
    const float* __restrict__ Whh,    // [GD][DH] (layer-selected)
    const float* __restrict__ hinit,  // [512]
    const float* __restrict__ cinit,  // [512]
    float* __restrict__ hseq,         // [64][512]
    float* __restrict__ comm)         // [64][512], zeroed before launch
{
    const int tid = threadIdx.x, r = blockIdx.x;
    const int kh = tid >> 7, rem = tid & 127;
    const int q = rem >> 5, jj = rem & 31;
    const int row = q * DH + r * 32 + jj;
    const int k0 = kh * 256;

    h2_t w2[128];
    {
        const float4* wr = (const float4*)(Whh + (long)row * DH + k0);
#pragma unroll
        for (int i = 0; i < 64; i++) {
            float4 v = wr[i];
            w2[2 * i]     = h2_t{(_Float16)v.x, (_Float16)v.y};
            w2[2 * i + 1] = h2_t{(_Float16)v.z, (_Float16)v.w};
        }
    }

    __shared__ __align__(16) _Float16 hsArr[DH];
    __shared__ float part[256];
    __shared__ float gate[128];
    hsArr[tid] = (_Float16)hinit[tid];
    hsArr[tid + 256] = (_Float16)hinit[tid + 256];
    float c = (tid < 32) ? cinit[r * 32 + tid] : 0.f;
    float pre_cur = (tid < 128) ? pre[row] : 0.f;
    float h_cur = 0.f;
    __syncthreads();

    for (int s = 0; s < T_STEPS; s++) {
        float acc = 0.f;
        const float4* hv = (const float4*)(hsArr + k0);
#pragma unroll
        for (int kk = 0; kk < 32; kk++) {
            float4 blk = hv[kk];
            const h2_t* hp = (const h2_t*)&blk;
            acc = fdot2f(w2[4 * kk + 0], hp[0], acc);
            acc = fdot2f(w2[4 * kk + 1], hp[1], acc);
            acc = fdot2f(w2[4 * kk + 2], hp[2], acc);
            acc = fdot2f(w2[4 * kk + 3], hp[3], acc);
        }
        part[tid] = acc;
        __syncthreads();
        if (tid < 128) {
            float g = part[tid] + part[tid + 128] + pre_cur;
            if (s + 1 < T_STEPS) pre_cur = pre[(long)(s + 1) * GD + row];
            gate[tid] = g;
        }
        __syncthreads();
        if (tid < 32) {
            int jg = r * 32 + tid;
            float gi = gate[tid], gf = gate[32 + tid], gg = gate[64 + tid], go = gate[96 + tid];
            c = sigf(gf) * c + sigf(gi) * tanh_fast(gg);
            h_cur = sigf(go) * tanh_fast(c);
            post_comm(&comm[(long)s * DH + jg], h_cur);
            hseq[(long)s * DH + jg] = h_cur;
            hsArr[jg] = (_Float16)h_cur;
        }
        if (s + 1 < T_STEPS) {
            if (tid < 224) {                       // remote rel offsets 32..255
                int idx = (r * 32 + 32 + tid) & 511;
                hsArr[idx] = (_Float16)poll_comm(&comm[(long)s * DH + idx]);
            }
            {                                      // remote rel offsets 256..511
                int idx = (r * 32 + 256 + tid) & 511;
                hsArr[idx] = (_Float16)poll_comm(&comm[(long)s * DH + idx]);
            }
        }
        __syncthreads();
    }
}

// ---------------------------------------------------------------------------
// Attention readout
// ---------------------------------------------------------------------------
__global__ void k_attn(const float* __restrict__ encK, const float* __restrict__ qs,
                       const float* __restrict__ v, const int* __restrict__ alens,
                       float* __restrict__ out)
{
    int t = blockIdx.x;
    int tid = threadIdx.x;
    int wave = tid >> 6, lane = tid & 63;
    int len = alens[t];
    const float* qt = qs + t * 256;
    for (int a = wave; a < A_DIM; a += 4) {
        const float* ek = encK + (long)(t * A_DIM + a) * 256;
        float sum = 0.f;
#pragma unroll
        for (int e = 0; e < 4; e++) {
            int d = lane * 4 + e;
            sum += v[d] * tanhf(ek[d] + qt[d]);
        }
        for (int off = 32; off; off >>= 1) sum += __shfl_down(sum, off, 64);
        if (lane == 0) out[t * A_DIM + a] = (a < len) ? sum : -1e10f;
    }
}

// ---------------------------------------------------------------------------
extern "C" void kernel_launch(void* const* d_in, const int* in_sizes, int n_in,
                              void* d_out, int out_size, void* d_ws, size_t ws_size,
                              hipStream_t stream)
{
    (void)in_sizes; (void)n_in; (void)out_size; (void)ws_size;
    const int*   lattice = (const int*)d_in[0];
    const int*   alens   = (const int*)d_in[1];
    const int*   inputs  = (const int*)d_in[2];
    const int*   gold    = (const int*)d_in[4];
    const int*   sos     = (const int*)d_in[5];
    const float* lat_emb = (const float*)d_in[6];
    const float* in_emb  = (const float*)d_in[7];
    const float* Wih0    = (const float*)d_in[8];
    const float* Whh0    = (const float*)d_in[9];
    const float* b0      = (const float*)d_in[10];
    const float* Wih1    = (const float*)d_in[11];
    const float* Whh1    = (const float*)d_in[12];
    const float* b1      = (const float*)d_in[13];
    const float* dWih    = (const float*)d_in[14];
    const float* dWhh    = (const float*)d_in[15];
    const float* db      = (const float*)d_in[16];
    const float* Wq      = (const float*)d_in[17];
    const float* Wk      = (const float*)d_in[18];
    const float* av      = (const float*)d_in[19];
    float* out = (float*)d_out;
    float* ws  = (float*)d_ws;

    // ws layout (floats) — total 3,770,368 floats = 15.08 MB (≤15.7 MB proven)
    float* comm  = ws;                  // 524288  [2][1024][256], reused per enc layer
    float* commD = ws + 524288;         // 65536   [2 layers][64][512]
    float* xbuf  = ws + 589824;         // 262144  x; later decoder scratch:
    float* dpre  = xbuf;                //   131072
    float* h0seq = xbuf + 131072;       //   32768
    float* h1seq = xbuf + 163840;       //   32768
    float* qseq  = xbuf + 196608;       //   16384
    float* pre   = ws + 851968;         // 2097152 (per-layer gate pre-activations)
    float* y0    = ws + 2949120;        // 524288  L0 output; reused as enc (L1 out)
    float* hdec  = ws + 3473408;        // 1024    [2][512]
    float* cdec  = ws + 3474432;        // 1024
    float* decin = ws + 3475456;        // 32768   [64][512]
    float* encK  = ws + 3508224;        // 262144

    // zero comm + commD (poisoned 0xAA before every launch)
    hipMemsetAsync(ws, 0, (524288 + 65536) * sizeof(float), stream);

    k_embed<<<1152, 256, 0, stream>>>(lattice, inputs, gold, sos, lat_emb, in_emb, xbuf, decin);

    // pre = x @ Wih0^T + b0  (both dirs)
    k_gemm<<<dim3(16, 16, 2), 256, 0, stream>>>(
        xbuf, 256, 0L, Wih0, 256, 1, (long)GE * 256, b0, GE,
        pre, GE, (long)SEQ * GE, SEQ, GE, 256);
    k_rec_enc<<<8, 256, 0, stream>>>(pre, Whh0, y0, hdec, cdec, comm);

    // re-zero comm for layer 1
    hipMemsetAsync(comm, 0, 524288 * sizeof(float), stream);

    // pre = y0 @ Wih1^T + b1
    k_gemm<<<dim3(16, 16, 2), 256, 0, stream>>>(
        y0, 512, 0L, Wih1, 512, 1, (long)GE * 512, b1, GE,
        pre, GE, (long)SEQ * GE, SEQ, GE, 512);
    // L1 output overwrites y0 region (y0 is dead after the GEMM above)
    k_rec_enc<<<8, 256, 0, stream>>>(pre, Whh1, y0, hdec + 512, cdec + 512, comm);

    // encK = enc @ Wk
    k_gemm<<<dim3(4, 16, 1), 256, 0, stream>>>(
        y0, 512, 0L, Wk, 1, 256, 0L, nullptr, 0,
        encK, 256, 0L, SEQ, 256, 512);

    // dpre = decin @ dWih[0]^T + db[0]
    k_gemm<<<dim3(32, 1, 1), 256, 0, stream>>>(
        decin, 512, 0L, dWih, 512, 1, 0L, db, 0,
        dpre, GD, 0L, T_STEPS, GD, 512);
    k_rec_dec<<<16, 256, 0, stream>>>(dpre, dWhh, hdec, cdec, h0seq, commD);

    // dpre = h0seq @ dWih[1]^T + db[1]
    k_gemm<<<dim3(32, 1, 1), 256, 0, stream>>>(
        h0seq, 512, 0L, dWih + (long)GD * 512, 512, 1, 0L, db + GD, 0,
        dpre, GD, 0L, T_STEPS, GD, 512);
    k_rec_dec<<<16, 256, 0, stream>>>(dpre, dWhh + (long)GD * 512, hdec + 512, cdec + 512,
                                      h1seq, commD + 32768);

    // q = h1seq @ Wq
    k_gemm<<<dim3(4, 1, 1), 256, 0, stream>>>(
        h1seq, 512, 0L, Wq, 1, 256, 0L, nullptr, 0,
        qseq, 256, 0L, T_STEPS, 256, 512);

    k_attn<<<64, 256, 0, stream>>>(encK, qseq, av, alens, out);
}